// Round 6
// baseline (711.528 us; speedup 1.0000x reference)
//
#include <hip/hip_runtime.h>

#define CHUNK 8192           // edges per block in coarse pass
#define BMAX 512             // max coarse buckets (N/256 <= 512)

// ---------------- coarse bucket histogram ----------------

__global__ __launch_bounds__(256) void k_coarse_hist(const int* __restrict__ dst, int E,
                                                     int* __restrict__ bc,
                                                     int* __restrict__ blockBase, int B) {
    __shared__ int cnt[BMAX];
    int t = threadIdx.x;
    cnt[t] = 0; cnt[t + 256] = 0;
    __syncthreads();
    int e0 = blockIdx.x * CHUNK;
#pragma unroll
    for (int it = 0; it < CHUNK / 256; ++it) {
        int e = e0 + it * 256 + t;
        if (e < E) atomicAdd(&cnt[dst[e] >> 8], 1);
    }
    __syncthreads();
    for (int b = t; b < B; b += 256) {
        int c = cnt[b];
        if (c > 0) blockBase[(size_t)blockIdx.x * B + b] = atomicAdd(&bc[b], c);
    }
}

// single block, 512 threads; exclusive scan in place (n <= 512)
__global__ void k_scan_bsums(int* bsums, int nb) {
    __shared__ int s[2][512];
    int t = threadIdx.x;
    int v = (t < nb) ? bsums[t] : 0;
    int p = 0;
    s[0][t] = v;
    __syncthreads();
    for (int off = 1; off < 512; off <<= 1) {
        s[p ^ 1][t] = s[p][t] + ((t >= off) ? s[p][t - off] : 0);
        p ^= 1;
        __syncthreads();
    }
    if (t < nb) bsums[t] = s[p][t] - v;  // exclusive
}

// ---------------- coarse scatter ----------------

__global__ __launch_bounds__(256) void k_coarse_scatter(const int* __restrict__ src,
                                                        const int* __restrict__ dst, int E,
                                                        const int* __restrict__ bucketBase,
                                                        const int* __restrict__ blockBase, int B,
                                                        unsigned int* __restrict__ ebuf) {
    __shared__ int run[BMAX];
    int t = threadIdx.x;
    run[t] = 0; run[t + 256] = 0;
    __syncthreads();
    int e0 = blockIdx.x * CHUNK;
#pragma unroll
    for (int it = 0; it < CHUNK / 256; ++it) {
        int e = e0 + it * 256 + t;
        if (e < E) {
            int d = dst[e];
            int b = d >> 8;
            int rank = atomicAdd(&run[b], 1);
            int pos = bucketBase[b] + blockBase[(size_t)blockIdx.x * B + b] + rank;
            ebuf[pos] = ((unsigned int)(d & 255) << 24) | (unsigned int)src[e];
        }
    }
}

// ---------------- per-node degree histogram + dinv from bucketed edges ----------------

__global__ __launch_bounds__(256) void k_bucket_hist(const unsigned int* __restrict__ ebuf,
                                                     const int* __restrict__ bucketBase,
                                                     int E, int N, int B,
                                                     int* __restrict__ hist,
                                                     float* __restrict__ dinv) {
    __shared__ int cnt[256];
    int t = threadIdx.x;
    int b = blockIdx.x;
    cnt[t] = 0;
    __syncthreads();
    int e0 = bucketBase[b];
    int e1 = (b + 1 < B) ? bucketBase[b + 1] : E;
    for (int e = e0 + t; e < e1; e += 256) atomicAdd(&cnt[ebuf[e] >> 24], 1);
    __syncthreads();
    int node = b * 256 + t;
    if (node < N) {
        hist[node] = cnt[t];
        dinv[node] = rsqrtf((float)(cnt[t] + 1));  // +1 self-loop
    }
}

// ---------------- fine scatter (fused rowStart scan): bucket -> CSR ----------------

__global__ __launch_bounds__(256) void k_fine_scatter(const unsigned int* __restrict__ ebuf,
                                                      const int* __restrict__ bucketBase,
                                                      const int* __restrict__ hist,
                                                      int E, int N, int B,
                                                      int* __restrict__ rowStart,
                                                      int* __restrict__ csr_src) {
    __shared__ int s[2][256];
    __shared__ int cnt[256];
    int t = threadIdx.x;
    int b = blockIdx.x;
    int node = b * 256 + t;
    int v = (node < N) ? hist[node] : 0;
    int p = 0;
    s[0][t] = v;
    __syncthreads();
    for (int off = 1; off < 256; off <<= 1) {
        s[p ^ 1][t] = s[p][t] + ((t >= off) ? s[p][t - off] : 0);
        p ^= 1;
        __syncthreads();
    }
    int rs = bucketBase[b] + s[p][t] - v;
    if (node < N) rowStart[node] = rs;
    cnt[t] = rs;
    __syncthreads();
    int e0 = bucketBase[b];
    int e1 = (b + 1 < B) ? bucketBase[b + 1] : E;
    for (int e = e0 + t; e < e1; e += 256) {
        unsigned int w = ebuf[e];
        int pos = atomicAdd(&cnt[w >> 24], 1);
        csr_src[pos] = (int)(w & 0xFFFFFFu);
    }
}

// ---------------- W1 re-block: Wb[kb][j][c][d] = W1[(kb*32+j*4+d)*16 + c] ----------------
// Makes the 16 lanes of a row-group read CONTIGUOUS 256B per b128-refill step.

__global__ void k_prepW(const float* __restrict__ W1, float* __restrict__ Wb) {
    int i = blockIdx.x * 256 + threadIdx.x;  // i = k*16 + c; 8192 total
    if (i >= 8192) return;
    int k = i >> 4, c = i & 15;
    Wb[(k >> 5) * 512 + ((k >> 2) & 7) * 64 + c * 4 + (k & 3)] = W1[i];
}

// ---------------- GEMM1: h1 = (X @ W1) * dinv[row] ----------------
// No LDS, no barriers. 16 lanes per row; lane c owns output column c; k is
// wave-uniform so all 16 lanes read the SAME x float4 (same-address -> one
// L1 line, broadcast). W comes from the pre-blocked Wb (L1-resident 32KB),
// 8 b128/lane per 32-k chunk, contiguous 256B across the lane group.
// 6250 blocks, tiny VGPR -> deep TLP hides all latency.

__global__ __launch_bounds__(256) void k_gemm1(const float* __restrict__ x,
                                               const float* __restrict__ Wb,
                                               const float* __restrict__ dinv,
                                               int N, float* __restrict__ h1) {
    const int t = threadIdx.x;
    const int c = t & 15;                       // output column
    const int row0 = blockIdx.x * 16 + (t >> 4);
    const int row = (row0 < N) ? row0 : N - 1;  // clamp; store guarded below
    const float* xr = x + (size_t)row * 512;

    float acc = 0.0f;
    for (int kb = 0; kb < 16; ++kb) {
        const float* xp = xr + kb * 32;
        const float* wp = Wb + kb * 512 + c * 4;
        float4 xv[8], wv[8];
#pragma unroll
        for (int j = 0; j < 8; ++j) {
            xv[j] = *(const float4*)(xp + j * 4);    // same addr across 16 lanes
            wv[j] = *(const float4*)(wp + j * 64);   // lanes contiguous 256B
        }
#pragma unroll
        for (int j = 0; j < 8; ++j) {
            acc = fmaf(xv[j].x, wv[j].x, acc);
            acc = fmaf(xv[j].y, wv[j].y, acc);
            acc = fmaf(xv[j].z, wv[j].z, acc);
            acc = fmaf(xv[j].w, wv[j].w, acc);
        }
    }

    if (row0 < N) h1[(size_t)row0 * 16 + c] = acc * dinv[row0];
}

// ---------------- Aggregation layer 1: relu1 = relu(di * sum(h1') + b1) ----------------

__global__ void k_gather1(const float* __restrict__ h1, const int* __restrict__ csr_src,
                          const int* __restrict__ rowStart, const int* __restrict__ hist,
                          const float* __restrict__ dinv, const float* __restrict__ b1,
                          int N, float* __restrict__ relu1) {
    int g = blockIdx.x * blockDim.x + threadIdx.x;
    int i = g >> 4, c = g & 15;
    if (i >= N) return;
    float ssum = h1[(size_t)i * 16 + c];  // self-loop (already * dinv[i])
    int e0 = rowStart[i], e1 = e0 + hist[i];
    for (int e = e0; e < e1; ++e) {
        int s = csr_src[e];
        ssum += h1[(size_t)s * 16 + c];
    }
    float v = fmaf(dinv[i], ssum, b1[c]);
    relu1[(size_t)i * 16 + c] = fmaxf(v, 0.0f);
}

// ---------------- h2 = (relu1 @ W2) * dinv[i]  (W2 [16,7]) ----------------

__global__ void k_h2(const float* __restrict__ relu1, const float* __restrict__ W2,
                     const float* __restrict__ dinv, int N, float* __restrict__ h2) {
    int i = blockIdx.x * blockDim.x + threadIdx.x;
    if (i >= N) return;
    float r[16];
#pragma unroll
    for (int q = 0; q < 4; ++q) {
        float4 v = *(const float4*)(relu1 + (size_t)i * 16 + q * 4);
        r[q * 4 + 0] = v.x; r[q * 4 + 1] = v.y; r[q * 4 + 2] = v.z; r[q * 4 + 3] = v.w;
    }
    float di = dinv[i];
#pragma unroll
    for (int c2 = 0; c2 < 7; ++c2) {
        float a = 0.0f;
#pragma unroll
        for (int c = 0; c < 16; ++c) a = fmaf(r[c], W2[c * 7 + c2], a);
        h2[(size_t)i * 7 + c2] = a * di;
    }
}

// ---------------- Aggregation layer 2: out = di * sum(h2') + b2 ----------------

__global__ void k_gather2(const float* __restrict__ h2, const int* __restrict__ csr_src,
                          const int* __restrict__ rowStart, const int* __restrict__ hist,
                          const float* __restrict__ dinv, const float* __restrict__ b2,
                          int N, float* __restrict__ out) {
    int g = blockIdx.x * blockDim.x + threadIdx.x;
    int i = g >> 3, c = g & 7;
    if (i >= N || c >= 7) return;
    float ssum = h2[(size_t)i * 7 + c];
    int e0 = rowStart[i], e1 = e0 + hist[i];
    for (int e = e0; e < e1; ++e) {
        int s = csr_src[e];
        ssum += h2[(size_t)s * 7 + c];
    }
    out[(size_t)i * 7 + c] = fmaf(dinv[i], ssum, b2[c]);
}

// ---------------- launch ----------------

extern "C" void kernel_launch(void* const* d_in, const int* in_sizes, int n_in,
                              void* d_out, int out_size, void* d_ws, size_t ws_size,
                              hipStream_t stream) {
    const float* x  = (const float*)d_in[0];
    const int*   ei = (const int*)d_in[1];
    const float* W1 = (const float*)d_in[2];
    const float* b1 = (const float*)d_in[3];
    const float* W2 = (const float*)d_in[4];
    const float* b2 = (const float*)d_in[5];
    float* out = (float*)d_out;

    const int N = in_sizes[0] / 512;
    const int E = in_sizes[1] / 2;
    const int* src = ei;       // edge_index[0]
    const int* dst = ei + E;   // edge_index[1]

    const int nb  = (N + 255) / 256;           // 391 node blocks == coarse buckets
    const int B   = nb;
    const int nbA = (E + CHUNK - 1) / CHUNK;   // 391 coarse blocks
    const int nbG = (N + 15) / 16;             // 6250 gemm1 blocks

    char* ws = (char*)d_ws;
    auto alloc = [&](size_t bytes) {
        char* p = ws;
        ws += (bytes + 511) & ~(size_t)511;
        return p;
    };
    // persistent region
    int*   hist      = (int*)alloc((size_t)N * 4);
    float* dinv      = (float*)alloc((size_t)N * 4);
    int*   rowStart  = (int*)alloc((size_t)N * 4);
    int*   bc        = (int*)alloc((size_t)(B + 1) * 4);
    int*   blockBase = (int*)alloc((size_t)nbA * B * 4);
    int*   csr_src   = (int*)alloc((size_t)E * 4);
    float* Wb        = (float*)alloc(8192 * 4);
    // overlapped region: ebuf (dead after fine_scatter) unions with h1/relu1/h2
    size_t featBytes = (size_t)N * 16 * 4 * 2 + (size_t)N * 7 * 4;
    size_t ebufBytes = (size_t)E * 4;
    char* regB = alloc(featBytes > ebufBytes ? featBytes : ebufBytes);
    unsigned int* ebuf = (unsigned int*)regB;
    float* h1    = (float*)regB;
    float* relu1 = h1 + (size_t)N * 16;
    float* h2    = relu1 + (size_t)N * 16;

    hipMemsetAsync(bc, 0, (size_t)B * 4, stream);
    k_prepW<<<32, 256, 0, stream>>>(W1, Wb);
    k_coarse_hist<<<nbA, 256, 0, stream>>>(dst, E, bc, blockBase, B);
    k_scan_bsums<<<1, 512, 0, stream>>>(bc, B);                       // bc -> bucketBase
    k_coarse_scatter<<<nbA, 256, 0, stream>>>(src, dst, E, bc, blockBase, B, ebuf);
    k_bucket_hist<<<B, 256, 0, stream>>>(ebuf, bc, E, N, B, hist, dinv);
    k_fine_scatter<<<B, 256, 0, stream>>>(ebuf, bc, hist, E, N, B, rowStart, csr_src);
    k_gemm1<<<nbG, 256, 0, stream>>>(x, Wb, dinv, N, h1);
    k_gather1<<<(N * 16 + 255) / 256, 256, 0, stream>>>(h1, csr_src, rowStart, hist, dinv, b1, N, relu1);
    k_h2<<<nb, 256, 0, stream>>>(relu1, W2, dinv, N, h2);
    k_gather2<<<(N * 8 + 255) / 256, 256, 0, stream>>>(h2, csr_src, rowStart, hist, dinv, b2, N, out);
}